// Round 2
// baseline (1031.740 us; speedup 1.0000x reference)
//
#include <hip/hip_runtime.h>
#include <math.h>

namespace {

constexpr int TSEQ   = 2048;
constexpr int DIN    = 16;
constexpr int NH1    = 5;
constexpr int NH2    = 50;
constexpr int NCLS   = 20;
constexpr int CHUNK  = 64;
constexpr int NCHUNK = TSEQ / CHUNK;
constexpr int BATCH  = 256;
constexpr int GSTR   = 80;          // padded gate-row stride: 80 mod 32 = 16 -> max 2-way (free)
constexpr int PROW   = 4 * GSTR;    // 320 floats per (buf,wave) partial region

// No clamp: exp(+inf)->inf, rcp(inf)->0 — still correct; inputs bounded.
__device__ __forceinline__ float fast_sigm(float x) {
    return __fdividef(1.f, 1.f + __expf(-x));
}
// tanh(x) = 2*sigm(2x) - 1
__device__ __forceinline__ float fast_tanh(float x) {
    return fmaf(2.f, fast_sigm(2.f * x), -1.f);
}

// quad_perm DPP: VALU-speed cross-lane within aligned quads.
template <int CTRL>
__device__ __forceinline__ float qperm(float v) {
    int i = __builtin_bit_cast(int, v);
    int r = __builtin_amdgcn_update_dpp(i, i, CTRL, 0xf, 0xf, false);
    return __builtin_bit_cast(float, r);
}
__device__ __forceinline__ float rdlane(float v, int lane) {
    return __builtin_bit_cast(float,
        __builtin_amdgcn_readlane(__builtin_bit_cast(int, v), lane));
}

// Step barrier: LDS-drain + s_barrier only (NO vmcnt drain). Waves 0-3 have
// no VMEM in flight inside the loop; wave 4's global x-prefetch stays
// outstanding across barriers (T4). Single asm so the compiler cannot
// separate the waitcnt from the barrier; "memory" orders all LDS ops.
#define STEP_BARRIER() asm volatile("s_waitcnt lgkmcnt(0)\n\ts_barrier" ::: "memory")

// One block = 5 waves = one batch element.
// Waves 0-3: split-K L2 matvec (unchanged math, padded-stride exchange).
// Wave 4:   runs layer-1 a full chunk ahead, streaming h1 into a
//           double-buffered LDS array; also reg-stages x two chunks ahead.
// Exactly ONE barrier per timestep, always in uniform control flow.
__global__ __launch_bounds__(320, 1) void lstm_fused_kernel(
    const float* __restrict__ x,     // (256,2048,16)
    const float* __restrict__ W1ih,  // (20,16)
    const float* __restrict__ W1hh,  // (20,5)
    const float* __restrict__ b1ih,  // (20)
    const float* __restrict__ b1hh,  // (20)
    const float* __restrict__ W2ih,  // (200,5)
    const float* __restrict__ W2hh,  // (200,50)
    const float* __restrict__ b2ih,  // (200)
    const float* __restrict__ b2hh,  // (200)
    const float* __restrict__ Wfc,   // (20,50)
    const float* __restrict__ bfc,   // (20)
    float* __restrict__ out)         // result(256,20) ++ last(256,50)
{
    const int b    = blockIdx.x;
    const int tid  = threadIdx.x;
    const int lane = tid & 63;
    const int wv   = tid >> 6;

    __shared__ __align__(16) float s_x[2][CHUNK * DIN];     // x dbuf (8 KB)
    __shared__ __align__(16) float s_part[2][4][PROW];      // partials dbuf (10 KB)
    __shared__ __align__(16) float s_h1[2][CHUNK][8];       // h1 stream dbuf (4 KB)
    __shared__ float s_h2[NH2];                             // final-h2 mirror

    const float* xb = x + (size_t)b * TSEQ * DIN;

    // ---- layer-1 setup: lane 4j+g owns row r = g*5+j (lanes 0..19) ----
    const int r1 = (lane < NCLS) ? ((lane & 3) * NH1 + (lane >> 2)) : 0;
    float w1h[NH1], w1x[DIN];
    #pragma unroll
    for (int j = 0; j < NH1; ++j) w1h[j] = W1hh[r1 * NH1 + j];
    #pragma unroll
    for (int d = 0; d < DIN; ++d) w1x[d] = W1ih[r1 * DIN + d];
    const float bias1 = b1ih[r1] + b1hh[r1];
    const bool  isg1  = ((lane & 3) == 2) && (lane < NCLS);
    const float isc1  = isg1 ? 2.f : 1.f;
    const float osc1  = isg1 ? 2.f : 1.f;
    const float off1  = isg1 ? -1.f : 0.f;
    float c1 = 0.f;
    float sh0v = 0.f, sh1v = 0.f, sh2v = 0.f, sh3v = 0.f, sh4v = 0.f;
    float4 xr0, xr1, xr2, xr3;      // wave-4 x staging regs (chunk c+2 in flight)

    // ---- L2 partial-phase weights: lane owns padded rows 4*lane..4*lane+3,
    //      K-slice = units 13*wv..13*wv+12 (zeros for wave 4 / pads) ----
    float wpw[4][13];
    #pragma unroll
    for (int i = 0; i < 4; ++i) {
        const int pr = 4 * lane + i;     // padded row 0..255
        const int pg = pr >> 6;          // gate
        const int pu = pr & 63;          // padded unit
        #pragma unroll
        for (int kk = 0; kk < 13; ++kk) {
            const int k = wv * 13 + kk;  // global K (h2 unit index)
            wpw[i][kk] = (wv < 4 && pu < NH2 && k < NH2)
                       ? W2hh[(pg * NH2 + pu) * NH2 + k] : 0.f;
        }
    }

    // ---- L2 combine-phase: lane = 4*ul+g -> unit u = 13*wv+ul ----
    const int  ul    = lane >> 2;
    const int  g     = lane & 3;
    const bool onc   = (ul < 13);
    const int  u     = (wv < 4 ? wv : 0) * 13 + (onc ? ul : 0);
    const bool ureal = (wv < 4) && onc && (u < NH2);
    float w2i[NH1];
    float bias2 = 0.f;
    if (ureal) {
        const int rr = g * NH2 + u;
        #pragma unroll
        for (int d = 0; d < NH1; ++d) w2i[d] = W2ih[rr * NH1 + d];
        bias2 = b2ih[rr] + b2hh[rr];
    } else {
        #pragma unroll
        for (int d = 0; d < NH1; ++d) w2i[d] = 0.f;
    }
    const bool  isg2 = (g == 2);
    const float isc2 = isg2 ? 2.f : 1.f;
    const float osc2 = isg2 ? 2.f : 1.f;
    const float off2 = isg2 ? -1.f : 0.f;

    // per-lane LDS pointers (hoisted): write = conflict-free b128,
    // gather = stride-80 rows (bank-conflict-free, see header comment)
    const int wvc = (wv < 4) ? wv : 0;
    float4* wpart = (float4*)(&s_part[0][wvc][GSTR * (lane >> 4)]) + (lane & 15);
    const int crow = g * GSTR + u;
    const float* rpart = &s_part[0][0][crow];

    float hsl[13];                       // wave's h2 K-slice (SGPRs)
    #pragma unroll
    for (int k = 0; k < 13; ++k) hsl[k] = 0.f;
    float c2 = 0.f;

    // ---- wave-4 L1 step: consume x(t) (uniform LDS reads), emit h1(t) ----
    // x-dot and h-dot are tree-structured to shorten wave 4's serial chain.
    auto l1_prod = [&](const float* xs, float* h1out) {
        float4 xv0 = *(const float4*)(xs + 0);
        float4 xv1 = *(const float4*)(xs + 4);
        float4 xv2 = *(const float4*)(xs + 8);
        float4 xv3 = *(const float4*)(xs + 12);
        float sa = fmaf(xv0.y, w1x[1],  xv0.x * w1x[0]);
        sa = fmaf(xv0.z, w1x[2], sa);  sa = fmaf(xv0.w, w1x[3], sa);
        float sb = fmaf(xv1.y, w1x[5],  xv1.x * w1x[4]);
        sb = fmaf(xv1.z, w1x[6], sb);  sb = fmaf(xv1.w, w1x[7], sb);
        float sc = fmaf(xv2.y, w1x[9],  xv2.x * w1x[8]);
        sc = fmaf(xv2.z, w1x[10], sc); sc = fmaf(xv2.w, w1x[11], sc);
        float sd = fmaf(xv3.y, w1x[13], xv3.x * w1x[12]);
        sd = fmaf(xv3.z, w1x[14], sd); sd = fmaf(xv3.w, w1x[15], sd);
        float ha = fmaf(sh1v, w1h[1], sh0v * w1h[0]);
        ha = fmaf(sh2v, w1h[2], ha);
        float hb = fmaf(sh4v, w1h[4], sh3v * w1h[3]);
        float g1 = ((sa + sb) + (sc + sd)) + ((ha + hb) + bias1);
        float act = fmaf(osc1, fast_sigm(isc1 * g1), off1);
        float f_ = qperm<0xB1>(act);
        float gg = qperm<0x4E>(act);
        float o_ = qperm<0x1B>(act);
        c1 = fmaf(f_, c1, act * gg);            // valid on lanes 4j+0
        float h1me = o_ * fast_tanh(c1);
        sh0v = rdlane(h1me, 0);  sh1v = rdlane(h1me, 4);
        sh2v = rdlane(h1me, 8);  sh3v = rdlane(h1me, 12);
        sh4v = rdlane(h1me, 16);
        if (g == 0 && lane < NCLS) h1out[lane >> 2] = h1me;
    };

    // L2 waves are the critical path; wave 4 has a full chunk of slack and
    // shares SIMD0 with wave 0 -> bias issue arbitration toward L2 (T5).
    if (wv < 4) __builtin_amdgcn_s_setprio(1);

    // ---- prologue: wave 4 stages chunk0/1, runs L1 chunk0, preloads chunk2 ----
    if (wv == 4) {
        xr0 = ((const float4*)(xb))[lane];
        xr1 = ((const float4*)(xb + 256))[lane];
        xr2 = ((const float4*)(xb + 512))[lane];
        xr3 = ((const float4*)(xb + 768))[lane];
        ((float4*)s_x[0])[lane]       = xr0;
        ((float4*)s_x[0])[64 + lane]  = xr1;
        ((float4*)s_x[0])[128 + lane] = xr2;
        ((float4*)s_x[0])[192 + lane] = xr3;
        for (int t = 0; t < CHUNK; ++t)
            l1_prod(&s_x[0][t * DIN], &s_h1[0][t][0]);
        xr0 = ((const float4*)(xb + 1024))[lane];
        xr1 = ((const float4*)(xb + 1280))[lane];
        xr2 = ((const float4*)(xb + 1536))[lane];
        xr3 = ((const float4*)(xb + 1792))[lane];
        ((float4*)s_x[1])[lane]       = xr0;
        ((float4*)s_x[1])[64 + lane]  = xr1;
        ((float4*)s_x[1])[128 + lane] = xr2;
        ((float4*)s_x[1])[192 + lane] = xr3;
        xr0 = ((const float4*)(xb + 2048))[lane];
        xr1 = ((const float4*)(xb + 2304))[lane];
        xr2 = ((const float4*)(xb + 2560))[lane];
        xr3 = ((const float4*)(xb + 2816))[lane];
    }
    STEP_BARRIER();   // keeps wave 4's chunk-2 loads in flight

    float4 h1a = make_float4(0.f, 0.f, 0.f, 0.f);
    float  h1e = 0.f;
    float  xp  = 0.f;     // x-side of L2 gate: bias2 + W2ih . h1 (pre-barrier)

    #pragma unroll 1
    for (int c = 0; c < NCHUNK; ++c) {
        const int  cur   = c & 1, nxt = cur ^ 1;
        const bool w4run = (wv == 4) && (c + 1 < NCHUNK);

        // wave 4: land staged x (chunk c+2) into s_x[cur]; kick loads for c+3.
        // (Both buffers' prior readers are done: same-wave program order.
        //  The compiler's counted vmcnt before first xr use waits only for
        //  loads issued a full chunk ago — effectively free.)
        if (wv == 4 && c + 2 < NCHUNK) {
            ((float4*)s_x[cur])[lane]       = xr0;
            ((float4*)s_x[cur])[64 + lane]  = xr1;
            ((float4*)s_x[cur])[128 + lane] = xr2;
            ((float4*)s_x[cur])[192 + lane] = xr3;
            if (c + 3 < NCHUNK) {
                const float* xc = xb + (size_t)(c + 3) * (CHUNK * DIN);
                xr0 = ((const float4*)(xc))[lane];
                xr1 = ((const float4*)(xc + 256))[lane];
                xr2 = ((const float4*)(xc + 512))[lane];
                xr3 = ((const float4*)(xc + 768))[lane];
            }
        }

        // pre-barrier phase: L2 partial + x-side gate (waves 0-3) or L1 (wave 4)
        #define L2_PART(BUF, TT)                                               \
            if (wv < 4) {                                                      \
                h1a = *(const float4*)(&s_h1[cur][TT][0]);  /* uniform addr */ \
                h1e = s_h1[cur][TT][4];                     /* -> broadcast */ \
                xp = fmaf(h1a.x, w2i[0], bias2);                               \
                xp = fmaf(h1a.y, w2i[1], xp);                                  \
                xp = fmaf(h1a.z, w2i[2], xp);                                  \
                xp = fmaf(h1a.w, w2i[3], xp);                                  \
                xp = fmaf(h1e,  w2i[4], xp);                                   \
                float a0 = 0.f, a1 = 0.f, a2 = 0.f, a3 = 0.f;                  \
                _Pragma("unroll")                                              \
                for (int kk = 0; kk < 13; ++kk) {                              \
                    a0 = fmaf(hsl[kk], wpw[0][kk], a0);                        \
                    a1 = fmaf(hsl[kk], wpw[1][kk], a1);                        \
                    a2 = fmaf(hsl[kk], wpw[2][kk], a2);                        \
                    a3 = fmaf(hsl[kk], wpw[3][kk], a3);                        \
                }                                                              \
                wpart[(BUF) * PROW] = make_float4(a0, a1, a2, a3);             \
            } else if (w4run) {                                                \
                l1_prod(&s_x[nxt][(TT) * DIN], &s_h1[nxt][TT][0]);             \
            }

        // post-barrier phase: gather + combine + activations (waves 0-3)
        #define L2_COMB(BUF)                                                   \
            if (wv < 4) {                                                      \
                const float p0 = rpart[(BUF) * (4 * PROW) + 0 * PROW];         \
                const float p1 = rpart[(BUF) * (4 * PROW) + 1 * PROW];         \
                const float p2 = rpart[(BUF) * (4 * PROW) + 2 * PROW];         \
                const float p3 = rpart[(BUF) * (4 * PROW) + 3 * PROW];         \
                float pre = ((p0 + p1) + (p2 + p3)) + xp;                      \
                float act2 = fmaf(osc2, fast_sigm(isc2 * pre), off2);          \
                float v1 = qperm<0xB1>(act2);                                  \
                float v2 = qperm<0x4E>(act2);                                  \
                float v3 = qperm<0x1B>(act2);                                  \
                c2 = fmaf(v1, c2, act2 * v2);                                  \
                float hn = v3 * fast_tanh(c2);                                 \
                _Pragma("unroll")                                              \
                for (int k = 0; k < 13; ++k) hsl[k] = rdlane(hn, 4 * k);       \
            }

        #pragma unroll 1
        for (int tt = 0; tt < CHUNK; tt += 2) {
            L2_PART(0, tt)
            STEP_BARRIER();
            L2_COMB(0)
            L2_PART(1, tt + 1)
            STEP_BARRIER();
            L2_COMB(1)
        }
        #undef L2_PART
        #undef L2_COMB
    }

    // ---- final h2: reconstruct per-lane value from wave-uniform hsl ----
    if (wv < 4) {
        float hv = 0.f;
        #pragma unroll
        for (int j = 0; j < 13; ++j)
            if (ul == j) hv = hsl[j];
        if (g == 0 && ureal) s_h2[u] = hv;
    }
    __syncthreads();

    // ---- outputs: result(256,20) @0, last(256,50) @5120 ----
    if (tid < NH2) out[BATCH * NCLS + b * NH2 + tid] = s_h2[tid];
    if (tid < NCLS) {
        float acc = bfc[tid];
        const float* wr = Wfc + tid * NH2;
        #pragma unroll
        for (int j = 0; j < NH2; ++j) acc = fmaf(s_h2[j], wr[j], acc);
        out[b * NCLS + tid] = acc;
    }
}

} // namespace

extern "C" void kernel_launch(void* const* d_in, const int* in_sizes, int n_in,
                              void* d_out, int out_size, void* d_ws, size_t ws_size,
                              hipStream_t stream) {
    (void)in_sizes; (void)n_in; (void)d_ws; (void)ws_size; (void)out_size;
    const float* x    = (const float*)d_in[0];
    const float* W1ih = (const float*)d_in[1];
    const float* W1hh = (const float*)d_in[2];
    const float* b1ih = (const float*)d_in[3];
    const float* b1hh = (const float*)d_in[4];
    const float* W2ih = (const float*)d_in[5];
    const float* W2hh = (const float*)d_in[6];
    const float* b2ih = (const float*)d_in[7];
    const float* b2hh = (const float*)d_in[8];
    const float* Wfc  = (const float*)d_in[9];
    const float* bfc  = (const float*)d_in[10];

    lstm_fused_kernel<<<dim3(BATCH), dim3(320), 0, stream>>>(
        x, W1ih, W1hh, b1ih, b1hh, W2ih, W2hh, b2ih, b2hh, Wfc, bfc,
        (float*)d_out);
}

// Round 3
// 795.173 us; speedup vs baseline: 1.2975x; 1.2975x over previous
//
#include <hip/hip_runtime.h>
#include <math.h>

namespace {

constexpr int TSEQ   = 2048;
constexpr int DIN    = 16;
constexpr int NH1    = 5;
constexpr int NH2    = 50;
constexpr int NCLS   = 20;
constexpr int CHUNK  = 64;
constexpr int NCHUNK = TSEQ / CHUNK;
constexpr int BATCH  = 256;
constexpr int GSTR   = 80;          // padded gate-row stride: 80 mod 32 = 16 -> max 2-way (free)
constexpr int PROW   = 4 * GSTR;    // 320 floats per (buf,wave) partial region

// No clamp: exp(+inf)->inf, rcp(inf)->0 — still correct; inputs bounded.
__device__ __forceinline__ float fast_sigm(float x) {
    return __fdividef(1.f, 1.f + __expf(-x));
}
// tanh(x) = 2*sigm(2x) - 1
__device__ __forceinline__ float fast_tanh(float x) {
    return fmaf(2.f, fast_sigm(2.f * x), -1.f);
}

// quad_perm DPP: VALU-speed cross-lane within aligned quads.
template <int CTRL>
__device__ __forceinline__ float qperm(float v) {
    int i = __builtin_bit_cast(int, v);
    int r = __builtin_amdgcn_update_dpp(i, i, CTRL, 0xf, 0xf, false);
    return __builtin_bit_cast(float, r);
}
__device__ __forceinline__ float rdlane(float v, int lane) {
    return __builtin_bit_cast(float,
        __builtin_amdgcn_readlane(__builtin_bit_cast(int, v), lane));
}

// Wave-4-only barrier: LDS-drain + s_barrier, NO vmcnt drain, so wave 4's
// global x prefetch stays in flight across the 64 barriers of a chunk.
// L2 waves use plain __syncthreads() (R2 showed asm barriers on the critical
// waves damage scheduling). Barrier COUNTS are identical across roles.
#define W4_BARRIER() asm volatile("s_waitcnt lgkmcnt(0)\n\ts_barrier" ::: "memory")

template <int N> struct IC { static constexpr int v = N; };

// One block = 5 waves = one batch element.
// Waves 0-3: split-K L2 matvec with ASYMMETRIC K-slices {6,15,15,14}:
//   wave 0 (shares SIMD0 with wave 4) gets the small slice so the per-SIMD
//   issue load is balanced: SIMD0 = small-L2 + L1 ~= SIMD1..3 = big-L2.
// Wave 4:   runs layer-1 a full chunk ahead, streaming h1 into a
//           double-buffered LDS array; also reg-stages x two chunks ahead.
// Exactly ONE barrier per timestep; same barrier count in every wave role.
__global__ __launch_bounds__(320, 1) void lstm_fused_kernel(
    const float* __restrict__ x,     // (256,2048,16)
    const float* __restrict__ W1ih,  // (20,16)
    const float* __restrict__ W1hh,  // (20,5)
    const float* __restrict__ b1ih,  // (20)
    const float* __restrict__ b1hh,  // (20)
    const float* __restrict__ W2ih,  // (200,5)
    const float* __restrict__ W2hh,  // (200,50)
    const float* __restrict__ b2ih,  // (200)
    const float* __restrict__ b2hh,  // (200)
    const float* __restrict__ Wfc,   // (20,50)
    const float* __restrict__ bfc,   // (20)
    float* __restrict__ out)         // result(256,20) ++ last(256,50)
{
    const int b    = blockIdx.x;
    const int tid  = threadIdx.x;
    const int lane = tid & 63;
    const int wv   = tid >> 6;

    __shared__ __align__(16) float s_x[2][CHUNK * DIN];     // x dbuf (8 KB)
    __shared__ __align__(16) float s_part[2][4][PROW];      // partials dbuf (10 KB)
    __shared__ __align__(16) float s_h1[2][CHUNK][8];       // h1 stream dbuf (4 KB)
    __shared__ float s_h2[NH2];                             // final-h2 mirror

    const float* xb = x + (size_t)b * TSEQ * DIN;

    if (wv == 4) {
        // ================= wave 4: L1 producer + x stager =================
        const int r1 = (lane < NCLS) ? ((lane & 3) * NH1 + (lane >> 2)) : 0;
        float w1h[NH1], w1x[DIN];
        #pragma unroll
        for (int j = 0; j < NH1; ++j) w1h[j] = W1hh[r1 * NH1 + j];
        #pragma unroll
        for (int d = 0; d < DIN; ++d) w1x[d] = W1ih[r1 * DIN + d];
        const float bias1 = b1ih[r1] + b1hh[r1];
        const bool  isg1  = ((lane & 3) == 2) && (lane < NCLS);
        const float isc1  = isg1 ? 2.f : 1.f;
        const float osc1  = isg1 ? 2.f : 1.f;
        const float off1  = isg1 ? -1.f : 0.f;
        float c1 = 0.f;
        float sh0v = 0.f, sh1v = 0.f, sh2v = 0.f, sh3v = 0.f, sh4v = 0.f;
        float4 xr0, xr1, xr2, xr3;

        // tree-structured dot to shorten wave 4's serial chain
        auto l1_prod = [&](const float* xs, float* h1out) {
            float4 xv0 = *(const float4*)(xs + 0);
            float4 xv1 = *(const float4*)(xs + 4);
            float4 xv2 = *(const float4*)(xs + 8);
            float4 xv3 = *(const float4*)(xs + 12);
            float sa = fmaf(xv0.y, w1x[1],  xv0.x * w1x[0]);
            sa = fmaf(xv0.z, w1x[2], sa);  sa = fmaf(xv0.w, w1x[3], sa);
            float sb = fmaf(xv1.y, w1x[5],  xv1.x * w1x[4]);
            sb = fmaf(xv1.z, w1x[6], sb);  sb = fmaf(xv1.w, w1x[7], sb);
            float sc = fmaf(xv2.y, w1x[9],  xv2.x * w1x[8]);
            sc = fmaf(xv2.z, w1x[10], sc); sc = fmaf(xv2.w, w1x[11], sc);
            float sd = fmaf(xv3.y, w1x[13], xv3.x * w1x[12]);
            sd = fmaf(xv3.z, w1x[14], sd); sd = fmaf(xv3.w, w1x[15], sd);
            float ha = fmaf(sh1v, w1h[1], sh0v * w1h[0]);
            ha = fmaf(sh2v, w1h[2], ha);
            float hb = fmaf(sh4v, w1h[4], sh3v * w1h[3]);
            float g1 = ((sa + sb) + (sc + sd)) + ((ha + hb) + bias1);
            float act = fmaf(osc1, fast_sigm(isc1 * g1), off1);
            float f_ = qperm<0xB1>(act);
            float gg = qperm<0x4E>(act);
            float o_ = qperm<0x1B>(act);
            c1 = fmaf(f_, c1, act * gg);            // valid on lanes 4j+0
            float h1me = o_ * fast_tanh(c1);
            sh0v = rdlane(h1me, 0);  sh1v = rdlane(h1me, 4);
            sh2v = rdlane(h1me, 8);  sh3v = rdlane(h1me, 12);
            sh4v = rdlane(h1me, 16);
            if ((lane & 3) == 0 && lane < NCLS) h1out[lane >> 2] = h1me;
        };

        // prologue: stage chunk0, run L1 chunk0, stage chunk1, preload chunk2
        xr0 = ((const float4*)(xb))[lane];
        xr1 = ((const float4*)(xb + 256))[lane];
        xr2 = ((const float4*)(xb + 512))[lane];
        xr3 = ((const float4*)(xb + 768))[lane];
        ((float4*)s_x[0])[lane]       = xr0;
        ((float4*)s_x[0])[64 + lane]  = xr1;
        ((float4*)s_x[0])[128 + lane] = xr2;
        ((float4*)s_x[0])[192 + lane] = xr3;
        for (int t = 0; t < CHUNK; ++t)
            l1_prod(&s_x[0][t * DIN], &s_h1[0][t][0]);
        xr0 = ((const float4*)(xb + 1024))[lane];
        xr1 = ((const float4*)(xb + 1280))[lane];
        xr2 = ((const float4*)(xb + 1536))[lane];
        xr3 = ((const float4*)(xb + 1792))[lane];
        ((float4*)s_x[1])[lane]       = xr0;
        ((float4*)s_x[1])[64 + lane]  = xr1;
        ((float4*)s_x[1])[128 + lane] = xr2;
        ((float4*)s_x[1])[192 + lane] = xr3;
        xr0 = ((const float4*)(xb + 2048))[lane];
        xr1 = ((const float4*)(xb + 2304))[lane];
        xr2 = ((const float4*)(xb + 2560))[lane];
        xr3 = ((const float4*)(xb + 2816))[lane];
        W4_BARRIER();                                       // matches L2 prologue

        #pragma unroll 1
        for (int c = 0; c < NCHUNK; ++c) {
            const int  cur   = c & 1, nxt = cur ^ 1;
            const bool w4run = (c + 1 < NCHUNK);
            if (c + 2 < NCHUNK) {
                ((float4*)s_x[cur])[lane]       = xr0;
                ((float4*)s_x[cur])[64 + lane]  = xr1;
                ((float4*)s_x[cur])[128 + lane] = xr2;
                ((float4*)s_x[cur])[192 + lane] = xr3;
                if (c + 3 < NCHUNK) {
                    const float* xc = xb + (size_t)(c + 3) * (CHUNK * DIN);
                    xr0 = ((const float4*)(xc))[lane];
                    xr1 = ((const float4*)(xc + 256))[lane];
                    xr2 = ((const float4*)(xc + 512))[lane];
                    xr3 = ((const float4*)(xc + 768))[lane];
                }
            }
            #pragma unroll 1
            for (int tt = 0; tt < CHUNK; tt += 2) {
                if (w4run) l1_prod(&s_x[nxt][tt * DIN], &s_h1[nxt][tt][0]);
                W4_BARRIER();
                if (w4run) l1_prod(&s_x[nxt][(tt + 1) * DIN], &s_h1[nxt][tt + 1][0]);
                W4_BARRIER();
            }
        }
    } else {
        // ================= waves 0-3: L2 split-K (compile-time slice) =====
        auto l2loop = [&](auto cntc, auto offc) {
            constexpr int CNT = decltype(cntc)::v;   // my K-slice size
            constexpr int OFF = decltype(offc)::v;   // my K-slice offset

            // partial-phase weights: lane owns padded rows 4*lane..4*lane+3
            float wpw[4][CNT];
            #pragma unroll
            for (int i = 0; i < 4; ++i) {
                const int pr = 4 * lane + i;
                const int pg = pr >> 6;
                const int pu = pr & 63;
                #pragma unroll
                for (int kk = 0; kk < CNT; ++kk)
                    wpw[i][kk] = (pu < NH2) ? W2hh[(pg * NH2 + pu) * NH2 + (OFF + kk)]
                                            : 0.f;
            }

            // combine-phase: lane = 4*ul+g -> unit u = OFF+ul (ul < CNT)
            const int  ul  = lane >> 2;
            const int  g   = lane & 3;
            const bool onc = (ul < CNT);
            const int  u   = OFF + (onc ? ul : 0);
            float w2i[NH1];
            float bias2 = 0.f;
            if (onc) {
                const int rr = g * NH2 + u;
                #pragma unroll
                for (int d = 0; d < NH1; ++d) w2i[d] = W2ih[rr * NH1 + d];
                bias2 = b2ih[rr] + b2hh[rr];
            } else {
                #pragma unroll
                for (int d = 0; d < NH1; ++d) w2i[d] = 0.f;
            }
            const bool  isg2 = (g == 2);
            const float isc2 = isg2 ? 2.f : 1.f;
            const float osc2 = isg2 ? 2.f : 1.f;
            const float off2 = isg2 ? -1.f : 0.f;

            float4* wpart = (float4*)(&s_part[0][wv][GSTR * (lane >> 4)]) + (lane & 15);
            const float* rpart = &s_part[0][0][g * GSTR + u];

            float hsl[CNT];
            #pragma unroll
            for (int k = 0; k < CNT; ++k) hsl[k] = 0.f;
            float c2 = 0.f;
            float4 h1a = make_float4(0.f, 0.f, 0.f, 0.f);
            float  h1e = 0.f;
            float  xp  = 0.f;    // x-side of L2 gate (hoisted off the post-barrier chain)

            __syncthreads();                                // prologue barrier

            #pragma unroll 1
            for (int c = 0; c < NCHUNK; ++c) {
                const int cur = c & 1;

                #define L2P(BUF, TT)                                           \
                {                                                              \
                    const float* h1p = &s_h1[cur][TT][0];                      \
                    h1a = *(const float4*)h1p;     /* uniform -> broadcast */  \
                    h1e = h1p[4];                                              \
                    xp = fmaf(h1a.x, w2i[0], bias2);                           \
                    xp = fmaf(h1a.y, w2i[1], xp);                              \
                    xp = fmaf(h1a.z, w2i[2], xp);                              \
                    xp = fmaf(h1a.w, w2i[3], xp);                              \
                    xp = fmaf(h1e,  w2i[4], xp);                               \
                    float a0 = 0.f, a1 = 0.f, a2 = 0.f, a3 = 0.f;              \
                    _Pragma("unroll")                                          \
                    for (int kk = 0; kk < CNT; ++kk) {                         \
                        a0 = fmaf(hsl[kk], wpw[0][kk], a0);                    \
                        a1 = fmaf(hsl[kk], wpw[1][kk], a1);                    \
                        a2 = fmaf(hsl[kk], wpw[2][kk], a2);                    \
                        a3 = fmaf(hsl[kk], wpw[3][kk], a3);                    \
                    }                                                          \
                    wpart[(BUF) * PROW] = make_float4(a0, a1, a2, a3);         \
                }

                #define L2C(BUF)                                               \
                {                                                              \
                    const float p0 = rpart[(BUF) * (4 * PROW) + 0 * PROW];     \
                    const float p1 = rpart[(BUF) * (4 * PROW) + 1 * PROW];     \
                    const float p2 = rpart[(BUF) * (4 * PROW) + 2 * PROW];     \
                    const float p3 = rpart[(BUF) * (4 * PROW) + 3 * PROW];     \
                    float pre = ((p0 + p1) + (p2 + p3)) + xp;                  \
                    float act2 = fmaf(osc2, fast_sigm(isc2 * pre), off2);      \
                    float v1 = qperm<0xB1>(act2);                              \
                    float v2 = qperm<0x4E>(act2);                              \
                    float v3 = qperm<0x1B>(act2);                              \
                    c2 = fmaf(v1, c2, act2 * v2);                              \
                    float hn = v3 * fast_tanh(c2);                             \
                    _Pragma("unroll")                                          \
                    for (int k = 0; k < CNT; ++k) hsl[k] = rdlane(hn, 4 * k);  \
                }

                #pragma unroll 1
                for (int tt = 0; tt < CHUNK; tt += 2) {
                    L2P(0, tt)
                    __syncthreads();
                    L2C(0)
                    L2P(1, tt + 1)
                    __syncthreads();
                    L2C(1)
                }
                #undef L2P
                #undef L2C
            }

            // epilogue: publish my units' final h2
            float hv = 0.f;
            #pragma unroll
            for (int j = 0; j < CNT; ++j)
                if (ul == j) hv = hsl[j];
            if (g == 0 && onc) s_h2[u] = hv;
        };

        if      (wv == 0) l2loop(IC<6>{},  IC<0>{});
        else if (wv == 1) l2loop(IC<15>{}, IC<6>{});
        else if (wv == 2) l2loop(IC<15>{}, IC<21>{});
        else              l2loop(IC<14>{}, IC<36>{});
    }

    __syncthreads();
    // ---- outputs: result(256,20) @0, last(256,50) @5120 ----
    if (tid < NH2) out[BATCH * NCLS + b * NH2 + tid] = s_h2[tid];
    if (tid < NCLS) {
        float acc = bfc[tid];
        const float* wr = Wfc + tid * NH2;
        #pragma unroll
        for (int j = 0; j < NH2; ++j) acc = fmaf(s_h2[j], wr[j], acc);
        out[b * NCLS + tid] = acc;
    }
}

} // namespace

extern "C" void kernel_launch(void* const* d_in, const int* in_sizes, int n_in,
                              void* d_out, int out_size, void* d_ws, size_t ws_size,
                              hipStream_t stream) {
    (void)in_sizes; (void)n_in; (void)d_ws; (void)ws_size; (void)out_size;
    const float* x    = (const float*)d_in[0];
    const float* W1ih = (const float*)d_in[1];
    const float* W1hh = (const float*)d_in[2];
    const float* b1ih = (const float*)d_in[3];
    const float* b1hh = (const float*)d_in[4];
    const float* W2ih = (const float*)d_in[5];
    const float* W2hh = (const float*)d_in[6];
    const float* b2ih = (const float*)d_in[7];
    const float* b2hh = (const float*)d_in[8];
    const float* Wfc  = (const float*)d_in[9];
    const float* bfc  = (const float*)d_in[10];

    lstm_fused_kernel<<<dim3(BATCH), dim3(320), 0, stream>>>(
        x, W1ih, W1hh, b1ih, b1hh, W2ih, W2hh, b2ih, b2hh, Wfc, bfc,
        (float*)d_out);
}

// Round 4
// 789.149 us; speedup vs baseline: 1.3074x; 1.0076x over previous
//
#include <hip/hip_runtime.h>
#include <math.h>

namespace {

constexpr int TSEQ   = 2048;
constexpr int DIN    = 16;
constexpr int NH1    = 5;
constexpr int NH2    = 50;
constexpr int NCLS   = 20;
constexpr int CHUNK  = 64;
constexpr int NCHUNK = TSEQ / CHUNK;
constexpr int BATCH  = 256;
constexpr int GSTR   = 80;          // padded gate-row stride: 80 mod 32 = 16 -> max 2-way (free)
constexpr int PROW   = 4 * GSTR;    // 320 floats per (buf,wave) partial region

// No clamp: exp(+inf)->inf, rcp(inf)->0 — still correct; inputs bounded.
__device__ __forceinline__ float fast_sigm(float x) {
    return __fdividef(1.f, 1.f + __expf(-x));
}
// tanh(x) = 2*sigm(2x) - 1
__device__ __forceinline__ float fast_tanh(float x) {
    return fmaf(2.f, fast_sigm(2.f * x), -1.f);
}

// quad_perm DPP: VALU-speed cross-lane within aligned quads.
template <int CTRL>
__device__ __forceinline__ float qperm(float v) {
    int i = __builtin_bit_cast(int, v);
    int r = __builtin_amdgcn_update_dpp(i, i, CTRL, 0xf, 0xf, false);
    return __builtin_bit_cast(float, r);
}
__device__ __forceinline__ float rdlane(float v, int lane) {
    return __builtin_bit_cast(float,
        __builtin_amdgcn_readlane(__builtin_bit_cast(int, v), lane));
}

// Wave-4-only barrier: LDS-drain + s_barrier, NO vmcnt drain, so wave 4's
// global x prefetch stays in flight across the 64 barriers of a chunk.
// L2 waves use plain __syncthreads() (R2 showed asm barriers on the critical
// waves damage scheduling). Barrier COUNTS are identical across roles.
#define W4_BARRIER() asm volatile("s_waitcnt lgkmcnt(0)\n\ts_barrier" ::: "memory")

template <int N> struct IC { static constexpr int v = N; };

// One block = 5 waves = one batch element.
// Waves 0-3: split-K L2 matvec with ASYMMETRIC K-slices {6,15,15,14}:
//   wave 0 (shares SIMD0 with wave 4) gets the small slice so the per-SIMD
//   issue load is balanced: SIMD0 = small-L2 + L1 ~= SIMD1..3 = big-L2.
// Wave 4:   runs layer-1 a full chunk ahead, streaming h1 into a
//           double-buffered LDS array; also reg-stages x two chunks ahead.
// R4: wpw weights pinned into VGPRs via loop-carried empty asm ("+v") — R3's
// VGPR_Count=48 < 60-weight demand proved the compiler was re-fetching the
// L2 weights every step on the critical waves.
__global__ __launch_bounds__(320, 1) void lstm_fused_kernel(
    const float* __restrict__ x,     // (256,2048,16)
    const float* __restrict__ W1ih,  // (20,16)
    const float* __restrict__ W1hh,  // (20,5)
    const float* __restrict__ b1ih,  // (20)
    const float* __restrict__ b1hh,  // (20)
    const float* __restrict__ W2ih,  // (200,5)
    const float* __restrict__ W2hh,  // (200,50)
    const float* __restrict__ b2ih,  // (200)
    const float* __restrict__ b2hh,  // (200)
    const float* __restrict__ Wfc,   // (20,50)
    const float* __restrict__ bfc,   // (20)
    float* __restrict__ out)         // result(256,20) ++ last(256,50)
{
    const int b    = blockIdx.x;
    const int tid  = threadIdx.x;
    const int lane = tid & 63;
    const int wv   = tid >> 6;

    __shared__ __align__(16) float s_x[2][CHUNK * DIN];     // x dbuf (8 KB)
    __shared__ __align__(16) float s_part[2][4][PROW];      // partials dbuf (10 KB)
    __shared__ __align__(16) float s_h1[2][CHUNK][8];       // h1 stream dbuf (4 KB)
    __shared__ float s_h2[NH2];                             // final-h2 mirror

    const float* xb = x + (size_t)b * TSEQ * DIN;

    if (wv == 4) {
        // ================= wave 4: L1 producer + x stager =================
        const int r1 = (lane < NCLS) ? ((lane & 3) * NH1 + (lane >> 2)) : 0;
        float w1h[NH1], w1x[DIN];
        #pragma unroll
        for (int j = 0; j < NH1; ++j) w1h[j] = W1hh[r1 * NH1 + j];
        #pragma unroll
        for (int d = 0; d < DIN; ++d) w1x[d] = W1ih[r1 * DIN + d];
        const float bias1 = b1ih[r1] + b1hh[r1];
        const bool  isg1  = ((lane & 3) == 2) && (lane < NCLS);
        const float isc1  = isg1 ? 2.f : 1.f;
        const float osc1  = isg1 ? 2.f : 1.f;
        const float off1  = isg1 ? -1.f : 0.f;
        float c1 = 0.f;
        float sh0v = 0.f, sh1v = 0.f, sh2v = 0.f, sh3v = 0.f, sh4v = 0.f;
        float4 xr0, xr1, xr2, xr3;

        // tree-structured dot to shorten wave 4's serial chain
        auto l1_prod = [&](const float* xs, float* h1out) {
            float4 xv0 = *(const float4*)(xs + 0);
            float4 xv1 = *(const float4*)(xs + 4);
            float4 xv2 = *(const float4*)(xs + 8);
            float4 xv3 = *(const float4*)(xs + 12);
            float sa = fmaf(xv0.y, w1x[1],  xv0.x * w1x[0]);
            sa = fmaf(xv0.z, w1x[2], sa);  sa = fmaf(xv0.w, w1x[3], sa);
            float sb = fmaf(xv1.y, w1x[5],  xv1.x * w1x[4]);
            sb = fmaf(xv1.z, w1x[6], sb);  sb = fmaf(xv1.w, w1x[7], sb);
            float sc = fmaf(xv2.y, w1x[9],  xv2.x * w1x[8]);
            sc = fmaf(xv2.z, w1x[10], sc); sc = fmaf(xv2.w, w1x[11], sc);
            float sd = fmaf(xv3.y, w1x[13], xv3.x * w1x[12]);
            sd = fmaf(xv3.z, w1x[14], sd); sd = fmaf(xv3.w, w1x[15], sd);
            float ha = fmaf(sh1v, w1h[1], sh0v * w1h[0]);
            ha = fmaf(sh2v, w1h[2], ha);
            float hb = fmaf(sh4v, w1h[4], sh3v * w1h[3]);
            float g1 = ((sa + sb) + (sc + sd)) + ((ha + hb) + bias1);
            float act = fmaf(osc1, fast_sigm(isc1 * g1), off1);
            float f_ = qperm<0xB1>(act);
            float gg = qperm<0x4E>(act);
            float o_ = qperm<0x1B>(act);
            c1 = fmaf(f_, c1, act * gg);            // valid on lanes 4j+0
            float h1me = o_ * fast_tanh(c1);
            sh0v = rdlane(h1me, 0);  sh1v = rdlane(h1me, 4);
            sh2v = rdlane(h1me, 8);  sh3v = rdlane(h1me, 12);
            sh4v = rdlane(h1me, 16);
            if ((lane & 3) == 0 && lane < NCLS) h1out[lane >> 2] = h1me;
        };

        // prologue: stage chunk0, run L1 chunk0, stage chunk1, preload chunk2
        xr0 = ((const float4*)(xb))[lane];
        xr1 = ((const float4*)(xb + 256))[lane];
        xr2 = ((const float4*)(xb + 512))[lane];
        xr3 = ((const float4*)(xb + 768))[lane];
        ((float4*)s_x[0])[lane]       = xr0;
        ((float4*)s_x[0])[64 + lane]  = xr1;
        ((float4*)s_x[0])[128 + lane] = xr2;
        ((float4*)s_x[0])[192 + lane] = xr3;
        for (int t = 0; t < CHUNK; ++t)
            l1_prod(&s_x[0][t * DIN], &s_h1[0][t][0]);
        xr0 = ((const float4*)(xb + 1024))[lane];
        xr1 = ((const float4*)(xb + 1280))[lane];
        xr2 = ((const float4*)(xb + 1536))[lane];
        xr3 = ((const float4*)(xb + 1792))[lane];
        ((float4*)s_x[1])[lane]       = xr0;
        ((float4*)s_x[1])[64 + lane]  = xr1;
        ((float4*)s_x[1])[128 + lane] = xr2;
        ((float4*)s_x[1])[192 + lane] = xr3;
        xr0 = ((const float4*)(xb + 2048))[lane];
        xr1 = ((const float4*)(xb + 2304))[lane];
        xr2 = ((const float4*)(xb + 2560))[lane];
        xr3 = ((const float4*)(xb + 2816))[lane];
        W4_BARRIER();                                       // matches L2 prologue

        #pragma unroll 1
        for (int c = 0; c < NCHUNK; ++c) {
            const int  cur   = c & 1, nxt = cur ^ 1;
            const bool w4run = (c + 1 < NCHUNK);
            if (c + 2 < NCHUNK) {
                ((float4*)s_x[cur])[lane]       = xr0;
                ((float4*)s_x[cur])[64 + lane]  = xr1;
                ((float4*)s_x[cur])[128 + lane] = xr2;
                ((float4*)s_x[cur])[192 + lane] = xr3;
                if (c + 3 < NCHUNK) {
                    const float* xc = xb + (size_t)(c + 3) * (CHUNK * DIN);
                    xr0 = ((const float4*)(xc))[lane];
                    xr1 = ((const float4*)(xc + 256))[lane];
                    xr2 = ((const float4*)(xc + 512))[lane];
                    xr3 = ((const float4*)(xc + 768))[lane];
                }
            }
            #pragma unroll 1
            for (int tt = 0; tt < CHUNK; tt += 2) {
                if (w4run) l1_prod(&s_x[nxt][tt * DIN], &s_h1[nxt][tt][0]);
                W4_BARRIER();
                if (w4run) l1_prod(&s_x[nxt][(tt + 1) * DIN], &s_h1[nxt][tt + 1][0]);
                W4_BARRIER();
            }
        }
    } else {
        // ================= waves 0-3: L2 split-K (compile-time slice) =====
        auto l2loop = [&](auto cntc, auto offc) {
            constexpr int CNT = decltype(cntc)::v;   // my K-slice size
            constexpr int OFF = decltype(offc)::v;   // my K-slice offset

            // partial-phase weights: lane owns padded rows 4*lane..4*lane+3
            float wpw[4][CNT];
            #pragma unroll
            for (int i = 0; i < 4; ++i) {
                const int pr = 4 * lane + i;
                const int pg = pr >> 6;
                const int pu = pr & 63;
                #pragma unroll
                for (int kk = 0; kk < CNT; ++kk)
                    wpw[i][kk] = (pu < NH2) ? W2hh[(pg * NH2 + pu) * NH2 + (OFF + kk)]
                                            : 0.f;
            }

            // combine-phase: lane = 4*ul+g -> unit u = OFF+ul (ul < CNT)
            const int  ul  = lane >> 2;
            const int  g   = lane & 3;
            const bool onc = (ul < CNT);
            const int  u   = OFF + (onc ? ul : 0);
            float w2i[NH1];
            float bias2 = 0.f;
            if (onc) {
                const int rr = g * NH2 + u;
                #pragma unroll
                for (int d = 0; d < NH1; ++d) w2i[d] = W2ih[rr * NH1 + d];
                bias2 = b2ih[rr] + b2hh[rr];
            } else {
                #pragma unroll
                for (int d = 0; d < NH1; ++d) w2i[d] = 0.f;
            }
            const bool  isg2 = (g == 2);
            const float isc2 = isg2 ? 2.f : 1.f;
            const float osc2 = isg2 ? 2.f : 1.f;
            const float off2 = isg2 ? -1.f : 0.f;

            float4* wpart = (float4*)(&s_part[0][wv][GSTR * (lane >> 4)]) + (lane & 15);
            const float* rpart = &s_part[0][0][g * GSTR + u];

            float hsl[CNT];
            #pragma unroll
            for (int k = 0; k < CNT; ++k) hsl[k] = 0.f;
            float c2 = 0.f;
            float4 h1a = make_float4(0.f, 0.f, 0.f, 0.f);
            float  h1e = 0.f;
            float  xp  = 0.f;    // x-side of L2 gate (hoisted off the post-barrier chain)

            __syncthreads();                                // prologue barrier

            // Loop-carried VGPR pin: "+v" may-modify forbids re-loading wpw
            // from memory; zero instructions, no memory clobber -> no
            // scheduling-barrier side effects.
            #define PIN_WPW()                                                  \
                _Pragma("unroll")                                              \
                for (int i_ = 0; i_ < 4; ++i_) {                               \
                    _Pragma("unroll")                                          \
                    for (int k_ = 0; k_ < CNT; ++k_)                           \
                        asm volatile("" : "+v"(wpw[i_][k_]));                  \
                }

            #pragma unroll 1
            for (int c = 0; c < NCHUNK; ++c) {
                const int cur = c & 1;

                #define L2P(BUF, TT)                                           \
                {                                                              \
                    const float* h1p = &s_h1[cur][TT][0];                      \
                    h1a = *(const float4*)h1p;     /* uniform -> broadcast */  \
                    h1e = h1p[4];                                              \
                    xp = fmaf(h1a.x, w2i[0], bias2);                           \
                    xp = fmaf(h1a.y, w2i[1], xp);                              \
                    xp = fmaf(h1a.z, w2i[2], xp);                              \
                    xp = fmaf(h1a.w, w2i[3], xp);                              \
                    xp = fmaf(h1e,  w2i[4], xp);                               \
                    float a0 = 0.f, a1 = 0.f, a2 = 0.f, a3 = 0.f;              \
                    _Pragma("unroll")                                          \
                    for (int kk = 0; kk < CNT; ++kk) {                         \
                        a0 = fmaf(hsl[kk], wpw[0][kk], a0);                    \
                        a1 = fmaf(hsl[kk], wpw[1][kk], a1);                    \
                        a2 = fmaf(hsl[kk], wpw[2][kk], a2);                    \
                        a3 = fmaf(hsl[kk], wpw[3][kk], a3);                    \
                    }                                                          \
                    wpart[(BUF) * PROW] = make_float4(a0, a1, a2, a3);         \
                }

                #define L2C(BUF)                                               \
                {                                                              \
                    const float p0 = rpart[(BUF) * (4 * PROW) + 0 * PROW];     \
                    const float p1 = rpart[(BUF) * (4 * PROW) + 1 * PROW];     \
                    const float p2 = rpart[(BUF) * (4 * PROW) + 2 * PROW];     \
                    const float p3 = rpart[(BUF) * (4 * PROW) + 3 * PROW];     \
                    float pre = ((p0 + p1) + (p2 + p3)) + xp;                  \
                    float act2 = fmaf(osc2, fast_sigm(isc2 * pre), off2);      \
                    float v1 = qperm<0xB1>(act2);                              \
                    float v2 = qperm<0x4E>(act2);                              \
                    float v3 = qperm<0x1B>(act2);                              \
                    c2 = fmaf(v1, c2, act2 * v2);                              \
                    float hn = v3 * fast_tanh(c2);                             \
                    _Pragma("unroll")                                          \
                    for (int k = 0; k < CNT; ++k) hsl[k] = rdlane(hn, 4 * k);  \
                }

                #pragma unroll 1
                for (int tt = 0; tt < CHUNK; tt += 2) {
                    PIN_WPW()
                    L2P(0, tt)
                    __syncthreads();
                    L2C(0)
                    L2P(1, tt + 1)
                    __syncthreads();
                    L2C(1)
                }
                #undef L2P
                #undef L2C
            }
            #undef PIN_WPW

            // epilogue: publish my units' final h2
            float hv = 0.f;
            #pragma unroll
            for (int j = 0; j < CNT; ++j)
                if (ul == j) hv = hsl[j];
            if (g == 0 && onc) s_h2[u] = hv;
        };

        if      (wv == 0) l2loop(IC<6>{},  IC<0>{});
        else if (wv == 1) l2loop(IC<15>{}, IC<6>{});
        else if (wv == 2) l2loop(IC<15>{}, IC<21>{});
        else              l2loop(IC<14>{}, IC<36>{});
    }

    __syncthreads();
    // ---- outputs: result(256,20) @0, last(256,50) @5120 ----
    if (tid < NH2) out[BATCH * NCLS + b * NH2 + tid] = s_h2[tid];
    if (tid < NCLS) {
        float acc = bfc[tid];
        const float* wr = Wfc + tid * NH2;
        #pragma unroll
        for (int j = 0; j < NH2; ++j) acc = fmaf(s_h2[j], wr[j], acc);
        out[b * NCLS + tid] = acc;
    }
}

} // namespace

extern "C" void kernel_launch(void* const* d_in, const int* in_sizes, int n_in,
                              void* d_out, int out_size, void* d_ws, size_t ws_size,
                              hipStream_t stream) {
    (void)in_sizes; (void)n_in; (void)d_ws; (void)ws_size; (void)out_size;
    const float* x    = (const float*)d_in[0];
    const float* W1ih = (const float*)d_in[1];
    const float* W1hh = (const float*)d_in[2];
    const float* b1ih = (const float*)d_in[3];
    const float* b1hh = (const float*)d_in[4];
    const float* W2ih = (const float*)d_in[5];
    const float* W2hh = (const float*)d_in[6];
    const float* b2ih = (const float*)d_in[7];
    const float* b2hh = (const float*)d_in[8];
    const float* Wfc  = (const float*)d_in[9];
    const float* bfc  = (const float*)d_in[10];

    lstm_fused_kernel<<<dim3(BATCH), dim3(320), 0, stream>>>(
        x, W1ih, W1hh, b1ih, b1hh, W2ih, W2hh, b2ih, b2hh, Wfc, bfc,
        (float*)d_out);
}